// Round 2
// baseline (390.329 us; speedup 1.0000x reference)
//
#include <hip/hip_runtime.h>

// ---------------------------------------------------------------------------
// GCN pipeline (bf16 buffers, fp32 accumulation), R15 = R14 + XCD-partitioned
// place:
//   K1  init: fill=0, Wt=bf16(W^T), zero row N of hs        (1 dispatch)
//   K2  place || GEMM1 [1:1 roles]. Place is dst-partitioned 4-way: part =
//       gi&3 -> blockIdx = 2*gi -> XCD = 2*(gi&3) (measured round-robin
//       blockIdx%8->XCD). All fill[]/srcs_pad writes for a dst range issue
//       from ONE XCD, so dirty 64B sectors write-combine in that L2 instead
//       of ping-ponging across non-coherent XCD L2s (R14 counters: 120MB
//       WRITE for 32MB of payload = every 4B write flushed a 64B sector).
//       Each block scans a 4096-edge chunk, filters to its dst quarter
//       (4x edge re-read, L3-absorbed).
//   K3  aggregate_ln1 -> h1  (wave/node; per-source dinv from fill[] at
//       gather time via fma; lanes >= count clamped to (s=N,e=0); writes dinv)
//   K4  GEMM2: hs2 = bf16((h1@W2)*dinv)   (hs overwritten, row N stays 0)
//   K5  aggregate_ln2 -> h2 (h1 buffer; pre-scaled rows, e=1/0)
//   K6  gate GEMM + fused dot -> gate[N]
//   K7  pool_partial (B*16): local online-softmax stats
//   K8  classify (B): merge + @Wc + bc
// Measured ceilings (6+ variants each): aggregate ~85us = random 256B-row
// gather fabric ceiling. Structures that cut resident-wave count regressed.
// ---------------------------------------------------------------------------

typedef unsigned short ushort_t;
typedef unsigned int uint_t;
typedef __attribute__((ext_vector_type(8))) short short8;   // 8 x bf16
typedef __attribute__((ext_vector_type(4))) float floatx4;  // MFMA acc

#define POOL_S 16
#define PAD_DEG 64      // padded CSR row stride (deg ~ Poisson(16); max ~45)
#define PLACE_CHUNK 4096  // edges per place block chunk (256 thr * 4 * int4)

__device__ inline ushort_t bf16_rn(float f) {
  uint_t u = __float_as_uint(f);
  u += 0x7fffu + ((u >> 16) & 1u);
  return (ushort_t)(u >> 16);
}
__device__ inline float bf16_lo(uint_t v) { return __uint_as_float(v << 16); }
__device__ inline float bf16_hi(uint_t v) { return __uint_as_float(v & 0xffff0000u); }
__device__ inline uint_t bf16_pack(float a, float b) {
  return (uint_t)bf16_rn(a) | ((uint_t)bf16_rn(b) << 16);
}

// ---------------- K1: init (fill=0, Wt prep, zero hs row N) ---------------
__global__ __launch_bounds__(256) void init_kernel(
    int* __restrict__ fill, const float* __restrict__ W1,
    const float* __restrict__ W2, const float* __restrict__ Wg1,
    ushort_t* __restrict__ Wt, uint_t* __restrict__ hs_rowN, int Np) {
  int id = blockIdx.x * 256 + threadIdx.x;
  if (id < Np) { fill[id] = 0; return; }
  int id2 = id - Np;
  if (id2 < 40960) {
    float v;
    if (id2 < 16384) {
      int n = id2 >> 7, k = id2 & 127;
      v = W1[k * 128 + n];
    } else if (id2 < 32768) {
      int i2 = id2 - 16384;
      int n = i2 >> 7, k = i2 & 127;
      v = W2[k * 128 + n];
    } else {
      int i2 = id2 - 32768;
      int n = i2 >> 7, k = i2 & 127;
      v = Wg1[k * 64 + n];
    }
    Wt[id2] = bf16_rn(v);
    return;
  }
  int id3 = id2 - 40960;
  if (id3 < 64) hs_rowN[id3] = 0;
}

// ---------------- GEMM tile body (K=128 fixed, Wt bf16 [n][128]) ----------
template <int TM, int NC, bool IN_F32, bool SCALE, bool BIASRELU, bool GATEDOT>
__device__ __forceinline__ void gemm_tile(
    const void* __restrict__ in, const ushort_t* __restrict__ Wt,
    const float* __restrict__ bias, const float* __restrict__ dinv,
    ushort_t* __restrict__ out, int M, int row0,
    const float* __restrict__ Wg2, const float* __restrict__ bg2,
    float* __restrict__ gate_out, short* As) {
  constexpr int CT = NC / 16;
  constexpr int RT = TM / 64;
  const int t = threadIdx.x;
#pragma unroll
  for (int i = 0; i < TM / 16; ++i) {
    int chunk = t + i * 256;
    int rr = chunk >> 4, c8 = (chunk & 15) * 8;
    int row = row0 + rr;
    short8 val = {0, 0, 0, 0, 0, 0, 0, 0};
    if (IN_F32) {
      const float* inf = (const float*)in;
      if (row < M) {
        float4 v0 = *(const float4*)(inf + (size_t)row * 128 + c8);
        float4 v1 = *(const float4*)(inf + (size_t)row * 128 + c8 + 4);
        val[0] = (short)bf16_rn(v0.x); val[1] = (short)bf16_rn(v0.y);
        val[2] = (short)bf16_rn(v0.z); val[3] = (short)bf16_rn(v0.w);
        val[4] = (short)bf16_rn(v1.x); val[5] = (short)bf16_rn(v1.y);
        val[6] = (short)bf16_rn(v1.z); val[7] = (short)bf16_rn(v1.w);
      }
    } else {
      const short* inb = (const short*)in;
      if (row < M) val = *(const short8*)(inb + (size_t)row * 128 + c8);
    }
    *(short8*)&As[rr * 136 + c8] = val;
  }
  __syncthreads();

  const int wave = t >> 6, lane = t & 63;
  const int m16 = lane & 15, quad = lane >> 4;
  floatx4 acc[RT][CT];
#pragma unroll
  for (int rt = 0; rt < RT; ++rt)
#pragma unroll
    for (int ct = 0; ct < CT; ++ct) acc[rt][ct] = (floatx4){0.f, 0.f, 0.f, 0.f};
#pragma unroll
  for (int ks = 0; ks < 4; ++ks) {
    int koff = ks * 32 + quad * 8;
    short8 a[RT];
#pragma unroll
    for (int rt = 0; rt < RT; ++rt)
      a[rt] = *(const short8*)&As[(wave * 16 + rt * 64 + m16) * 136 + koff];
#pragma unroll
    for (int ct = 0; ct < CT; ++ct) {
      short8 b = *(const short8*)((const short*)Wt + (size_t)(ct * 16 + m16) * 128 + koff);
#pragma unroll
      for (int rt = 0; rt < RT; ++rt)
        acc[rt][ct] = __builtin_amdgcn_mfma_f32_16x16x32_bf16(a[rt], b, acc[rt][ct], 0, 0, 0);
    }
  }

  float bv[CT];
  if (BIASRELU) {
#pragma unroll
    for (int ct = 0; ct < CT; ++ct) bv[ct] = bias[ct * 16 + m16];
  }

  if (GATEDOT) {
    float w2[CT];
#pragma unroll
    for (int ct = 0; ct < CT; ++ct) w2[ct] = Wg2[ct * 16 + m16];
    float bg2v = bg2[0];
#pragma unroll
    for (int rt = 0; rt < RT; ++rt) {
#pragma unroll
      for (int reg = 0; reg < 4; ++reg) {
        float p = 0.f;
#pragma unroll
        for (int ct = 0; ct < CT; ++ct)
          p += fmaxf(acc[rt][ct][reg] + bv[ct], 0.f) * w2[ct];
        p += __shfl_xor(p, 1);
        p += __shfl_xor(p, 2);
        p += __shfl_xor(p, 4);
        p += __shfl_xor(p, 8);
        if (m16 == 0) {
          int row = row0 + wave * 16 + rt * 64 + quad * 4 + reg;
          if (row < M) gate_out[row] = p + bg2v;
        }
      }
    }
    return;
  }

#pragma unroll
  for (int rt = 0; rt < RT; ++rt) {
#pragma unroll
    for (int reg = 0; reg < 4; ++reg) {
      int row = row0 + wave * 16 + rt * 64 + quad * 4 + reg;
      if (row < M) {
        float mult = SCALE ? dinv[row] : 1.f;
#pragma unroll
        for (int ct = 0; ct < CT; ++ct) {
          float v = acc[rt][ct][reg];
          if (BIASRELU) v = fmaxf(v + bv[ct], 0.f);
          else if (SCALE) v *= mult;
          out[(size_t)row * NC + ct * 16 + m16] = bf16_rn(v);
        }
      }
    }
  }
}

// ---------------- K2: place (dst-partitioned, XCD-local) || GEMM1 ---------
__global__ __launch_bounds__(256) void place_gemm1_kernel(
    const int* __restrict__ src, const int* __restrict__ dst,
    int* __restrict__ fill, int* __restrict__ srcs_pad, int E,
    const float* __restrict__ x, const ushort_t* __restrict__ Wt,
    ushort_t* __restrict__ hs, int M, int nPlace, int nGemm, int quarterN) {
  __shared__ short As[64 * 136];
  int b = blockIdx.x;
  int gi = b >> 1;
  if (b & 1) {
    if (gi < nGemm)
      gemm_tile<64, 128, true, false, false, false>(
          x, Wt, nullptr, nullptr, hs, M, gi * 64, nullptr, nullptr, nullptr, As);
    return;
  }
  if (gi < nPlace) {
    // part = gi&3 -> blockIdx = 2*gi -> XCD = (2*gi)%8 = 2*(gi&3): each dst
    // quarter is written from exactly one XCD -> L2 write combining.
    const int part = gi & 3;
    const int chunk = gi >> 2;
    const int lo = part * quarterN;
    const int hi = (part == 3) ? M : lo + quarterN;
    const int base = chunk * PLACE_CHUNK;
#pragma unroll
    for (int k = 0; k < 4; ++k) {
      int e0 = base + (threadIdx.x + k * 256) * 4;
      if (e0 + 3 < E) {
        int4 d4 = *(const int4*)(dst + e0);
        int4 s4 = *(const int4*)(src + e0);
        if (d4.x >= lo && d4.x < hi) {
          int p = atomicAdd(&fill[d4.x], 1);
          if (p < PAD_DEG) srcs_pad[(size_t)d4.x * PAD_DEG + p] = s4.x;
        }
        if (d4.y >= lo && d4.y < hi) {
          int p = atomicAdd(&fill[d4.y], 1);
          if (p < PAD_DEG) srcs_pad[(size_t)d4.y * PAD_DEG + p] = s4.y;
        }
        if (d4.z >= lo && d4.z < hi) {
          int p = atomicAdd(&fill[d4.z], 1);
          if (p < PAD_DEG) srcs_pad[(size_t)d4.z * PAD_DEG + p] = s4.z;
        }
        if (d4.w >= lo && d4.w < hi) {
          int p = atomicAdd(&fill[d4.w], 1);
          if (p < PAD_DEG) srcs_pad[(size_t)d4.w * PAD_DEG + p] = s4.w;
        }
      } else {
        for (int j = 0; j < 4; ++j) {
          int e = e0 + j;
          if (e < E) {
            int d = dst[e];
            if (d >= lo && d < hi) {
              int pos = atomicAdd(&fill[d], 1);
              if (pos < PAD_DEG) srcs_pad[(size_t)d * PAD_DEG + pos] = src[e];
            }
          }
        }
      }
    }
  }
}

// ---------------- standalone MFMA GEMM (GEMM2, gate) ----------------------
template <int NC, bool SCALE, bool BIASRELU, bool GATEDOT>
__global__ __launch_bounds__(256) void gemm_mfma_kernel(
    const ushort_t* __restrict__ in, const ushort_t* __restrict__ Wt,
    const float* __restrict__ bias, const float* __restrict__ dinv,
    ushort_t* __restrict__ out, int M,
    const float* __restrict__ Wg2, const float* __restrict__ bg2,
    float* __restrict__ gate_out) {
  __shared__ short As[128 * 136];
  gemm_tile<128, NC, false, SCALE, BIASRELU, GATEDOT>(
      in, Wt, bias, dinv, out, M, blockIdx.x * 128, Wg2, bg2, gate_out, As);
}

// ---------------- aggregate + LN + ReLU -----------------------------------
// wave per node; srcs row preloaded into one register; indices + per-edge
// scale factors broadcast via shfl. Lanes >= count are clamped in-register to
// (s=N, e=0): no sentinel-padding pass, no OOB on stale srcs_pad slots.
// PERSRC=true : gathered rows are raw (x@W1); scale each by dinv[s] computed
//               from fill[s] (L2-resident), self row by dv; writes dinv[n].
// PERSRC=false: gathered rows pre-scaled by GEMM2 epilogue; e = 1/0 only.
__device__ __forceinline__ void fma8(float* a, uint4 v, float e) {
  a[0] = fmaf(bf16_lo(v.x), e, a[0]); a[1] = fmaf(bf16_hi(v.x), e, a[1]);
  a[2] = fmaf(bf16_lo(v.y), e, a[2]); a[3] = fmaf(bf16_hi(v.y), e, a[3]);
  a[4] = fmaf(bf16_lo(v.z), e, a[4]); a[5] = fmaf(bf16_hi(v.z), e, a[5]);
  a[6] = fmaf(bf16_lo(v.w), e, a[6]); a[7] = fmaf(bf16_hi(v.w), e, a[7]);
}

template <bool PERSRC>
__global__ __launch_bounds__(256) void aggregate_ln_kernel(
    const ushort_t* __restrict__ hs, const int* __restrict__ fill,
    const int* __restrict__ srcs_pad, float* __restrict__ dinv,
    const float* __restrict__ bias, const float* __restrict__ gamma,
    const float* __restrict__ beta, ushort_t* __restrict__ out, int N) {
  int n = (blockIdx.x * 256 + threadIdx.x) >> 6;
  int lane = threadIdx.x & 63;
  if (n >= N) return;
  const int col = lane & 15, epar = lane >> 4;
  const uint4* hs4 = (const uint4*)hs;  // 16 uint4 per row; row N is zeros
  int sreg = srcs_pad[(size_t)n * PAD_DEG + lane];  // whole padded row
  int count = fill[n];
  if (count > PAD_DEG) count = PAD_DEG;
  const int K = (count + 3) & ~3;  // wave-uniform, multiple of 4
  float dv = rsqrtf((float)(count + 1));
  // per-lane clamp + scale precompute (predicated: stale sreg never loads)
  int sc = N;
  float dreg = 0.f;
  if (lane < count) {
    sc = sreg;
    if (PERSRC) dreg = rsqrtf((float)(fill[sc] + 1));
    else        dreg = 1.f;
  }
  float a[8] = {0.f, 0.f, 0.f, 0.f, 0.f, 0.f, 0.f, 0.f};
  int i = epar;
  for (; i + 12 < K; i += 16) {  // 4 edges per lane in flight
    int s0 = __shfl(sc, i);       float e0 = __shfl(dreg, i);
    int s1 = __shfl(sc, i + 4);   float e1 = __shfl(dreg, i + 4);
    int s2 = __shfl(sc, i + 8);   float e2 = __shfl(dreg, i + 8);
    int s3 = __shfl(sc, i + 12);  float e3 = __shfl(dreg, i + 12);
    uint4 v0 = hs4[(size_t)s0 * 16 + col];
    uint4 v1 = hs4[(size_t)s1 * 16 + col];
    uint4 v2 = hs4[(size_t)s2 * 16 + col];
    uint4 v3 = hs4[(size_t)s3 * 16 + col];
    fma8(a, v0, e0); fma8(a, v1, e1); fma8(a, v2, e2); fma8(a, v3, e3);
  }
  for (; i < K; i += 4) {
    int s = __shfl(sc, i);
    float e = __shfl(dreg, i);
    uint4 v = hs4[(size_t)s * 16 + col];
    fma8(a, v, e);
  }
#pragma unroll
  for (int k = 0; k < 8; ++k) {
    a[k] += __shfl_xor(a[k], 16);
    a[k] += __shfl_xor(a[k], 32);
  }
  {
    uint4 sv = hs4[(size_t)n * 16 + col];
    fma8(a, sv, PERSRC ? dv : 1.f);  // self loop
  }
  if (PERSRC && lane == 0) dinv[n] = dv;  // for GEMM2 epilogue
  float4 b0 = *(const float4*)(bias + 8 * col);
  float4 b1 = *(const float4*)(bias + 8 * col + 4);
  float y[8];
  y[0] = a[0] * dv + b0.x; y[1] = a[1] * dv + b0.y;
  y[2] = a[2] * dv + b0.z; y[3] = a[3] * dv + b0.w;
  y[4] = a[4] * dv + b1.x; y[5] = a[5] * dv + b1.y;
  y[6] = a[6] * dv + b1.z; y[7] = a[7] * dv + b1.w;
  float s1 = 0.f, s2 = 0.f;
#pragma unroll
  for (int k = 0; k < 8; ++k) { s1 += y[k]; s2 += y[k] * y[k]; }
#pragma unroll
  for (int off = 1; off <= 8; off <<= 1) {
    s1 += __shfl_xor(s1, off);
    s2 += __shfl_xor(s2, off);
  }
  float mu = s1 * (1.f / 128.f);
  float var = s2 * (1.f / 128.f) - mu * mu;
  float rinv = rsqrtf(var + 1e-5f);
  float4 g0 = *(const float4*)(gamma + 8 * col);
  float4 g1 = *(const float4*)(gamma + 8 * col + 4);
  float4 e0 = *(const float4*)(beta + 8 * col);
  float4 e1 = *(const float4*)(beta + 8 * col + 4);
  float o[8];
  o[0] = fmaxf((y[0] - mu) * rinv * g0.x + e0.x, 0.f);
  o[1] = fmaxf((y[1] - mu) * rinv * g0.y + e0.y, 0.f);
  o[2] = fmaxf((y[2] - mu) * rinv * g0.z + e0.z, 0.f);
  o[3] = fmaxf((y[3] - mu) * rinv * g0.w + e0.w, 0.f);
  o[4] = fmaxf((y[4] - mu) * rinv * g1.x + e1.x, 0.f);
  o[5] = fmaxf((y[5] - mu) * rinv * g1.y + e1.y, 0.f);
  o[6] = fmaxf((y[6] - mu) * rinv * g1.z + e1.z, 0.f);
  o[7] = fmaxf((y[7] - mu) * rinv * g1.w + e1.w, 0.f);
  if (epar == 0) {
    uint4 pk;
    pk.x = bf16_pack(o[0], o[1]); pk.y = bf16_pack(o[2], o[3]);
    pk.z = bf16_pack(o[4], o[5]); pk.w = bf16_pack(o[6], o[7]);
    ((uint4*)out)[(size_t)n * 16 + col] = pk;
  }
}

// ---------------- pooling: local online-softmax partials + merge ----------
__device__ inline int lower_bound_i(const int* a, int n, int key) {
  int lo = 0, hi = n;
  while (lo < hi) {
    int mid = (lo + hi) >> 1;
    if (a[mid] < key) lo = mid + 1; else hi = mid;
  }
  return lo;
}

// K7: grid B*POOL_S. Local stats: m_k (max), d_k (sum exp), S_k[128].
__global__ __launch_bounds__(256) void pool_partial_kernel(
    const ushort_t* __restrict__ h2, const float* __restrict__ gate,
    const int* __restrict__ batch, float* __restrict__ partial,
    float2* __restrict__ pstat, int N) {
  int g = blockIdx.x / POOL_S, sub = blockIdx.x % POOL_S;
  int t = threadIdx.x;
  __shared__ float redx[256];
  __shared__ float redy[256];
  __shared__ float s_m;
  int lo = lower_bound_i(batch, N, g);
  int hi = lower_bound_i(batch, N, g + 1);
  int len = hi - lo;
  int chunk = (len + POOL_S - 1) / POOL_S;
  int a = lo + sub * chunk;
  int b = a + chunk < hi ? a + chunk : hi;
  float m = -3.4e38f;
  for (int i = a + t; i < b; i += 256) m = fmaxf(m, gate[i]);
  redx[t] = m;
  __syncthreads();
  for (int off = 128; off; off >>= 1) {
    if (t < off) redx[t] = fmaxf(redx[t], redx[t + off]);
    __syncthreads();
  }
  if (t == 0) s_m = redx[0];
  __syncthreads();
  float gmax = s_m;
  __syncthreads();
  float ssum = 0.f;
  for (int i = a + t; i < b; i += 256) ssum += expf(gate[i] - gmax);
  redx[t] = ssum;
  __syncthreads();
  for (int off = 128; off; off >>= 1) {
    if (t < off) redx[t] += redx[t + off];
    __syncthreads();
  }
  float denom = redx[0];
  __syncthreads();
  int p = t & 63, strm = t >> 6;
  const uint_t* h2u = (const uint_t*)h2;
  float accx = 0.f, accy = 0.f;
  int i = a + strm;
  for (; i + 8 <= b; i += 8) {
    float e0 = expf(gate[i] - gmax);
    float e1 = expf(gate[i + 4] - gmax);
    uint_t v0 = h2u[(size_t)i * 64 + p];
    uint_t v1 = h2u[(size_t)(i + 4) * 64 + p];
    accx += e0 * bf16_lo(v0) + e1 * bf16_lo(v1);
    accy += e0 * bf16_hi(v0) + e1 * bf16_hi(v1);
  }
  for (; i < b; i += 4) {
    float e = expf(gate[i] - gmax);
    uint_t v = h2u[(size_t)i * 64 + p];
    accx += e * bf16_lo(v);
    accy += e * bf16_hi(v);
  }
  redx[t] = accx;
  redy[t] = accy;
  __syncthreads();
  if (t < 64) {
    float px = redx[t] + redx[t + 64] + redx[t + 128] + redx[t + 192];
    float py = redy[t] + redy[t + 64] + redy[t + 128] + redy[t + 192];
    float* dstp = partial + (size_t)blockIdx.x * 128;
    dstp[2 * t] = px;
    dstp[2 * t + 1] = py;
  }
  if (t == 0) pstat[blockIdx.x] = make_float2(gmax, denom);
}

// K8: merge partials with exp(m_k - M) rescale, classifier
__global__ __launch_bounds__(128) void classify_kernel(
    const float* __restrict__ partial, const float2* __restrict__ pstat,
    const float* __restrict__ Wc, const float* __restrict__ bc,
    float* __restrict__ out) {
  int g = blockIdx.x, t = threadIdx.x;
  __shared__ float pooled[128];
  __shared__ float wgt[POOL_S];
  __shared__ float s_inv;
  if (t == 0) {
    float M = -3.4e38f;
    float2 st[POOL_S];
#pragma unroll
    for (int k = 0; k < POOL_S; ++k) {
      st[k] = pstat[g * POOL_S + k];
      M = fmaxf(M, st[k].x);
    }
    float total = 0.f;
#pragma unroll
    for (int k = 0; k < POOL_S; ++k) {
      float w = expf(st[k].x - M);
      wgt[k] = w;
      total += st[k].y * w;
    }
    s_inv = total > 0.f ? 1.f / total : 0.f;
  }
  __syncthreads();
  float inv = s_inv;
  float s = 0.f;
#pragma unroll
  for (int k = 0; k < POOL_S; ++k)
    s += partial[((size_t)g * POOL_S + k) * 128 + t] * wgt[k];
  pooled[t] = s * inv;
  __syncthreads();
  if (t < 16) {
    float o = bc[t];
    for (int ff = 0; ff < 128; ++ff) o = fmaf(pooled[ff], Wc[ff * 16 + t], o);
    out[g * 16 + t] = o;
  }
}

// ---------------- host launcher ----------------
extern "C" void kernel_launch(void* const* d_in, const int* in_sizes, int n_in,
                              void* d_out, int out_size, void* d_ws, size_t ws_size,
                              hipStream_t stream) {
  const float* x   = (const float*)d_in[0];
  const int*   ei  = (const int*)d_in[1];
  const int*   bat = (const int*)d_in[2];
  const float* W1  = (const float*)d_in[3];
  const float* b1  = (const float*)d_in[4];
  const float* g1  = (const float*)d_in[5];
  const float* be1 = (const float*)d_in[6];
  const float* W2  = (const float*)d_in[7];
  const float* b2  = (const float*)d_in[8];
  const float* g2  = (const float*)d_in[9];
  const float* be2 = (const float*)d_in[10];
  const float* Wg1 = (const float*)d_in[11];
  const float* bg1 = (const float*)d_in[12];
  const float* Wg2 = (const float*)d_in[13];
  const float* bg2 = (const float*)d_in[14];
  const float* Wc  = (const float*)d_in[15];
  const float* bc  = (const float*)d_in[16];

  const int N = in_sizes[0] / 128;
  const int E = in_sizes[1] / 2;
  const int B = out_size / 16;
  const int* src = ei;
  const int* dst = ei + E;

  const int Np = (N + 3) & ~3;

  int* fill      = (int*)d_ws;                       // Np
  float* dinv    = (float*)(fill + Np);              // Np
  float* gatep   = dinv + Np;                        // Np
  float2* pstat  = (float2*)(gatep + Np);            // B*POOL_S
  float* ppart   = (float*)(pstat + B * POOL_S);     // B*POOL_S*128
  int* srcs_pad  = (int*)(ppart + (size_t)B * POOL_S * 128);  // N*PAD_DEG
  ushort_t* Wt   = (ushort_t*)(srcs_pad + (size_t)N * PAD_DEG);  // 40960
  ushort_t* hs   = Wt + 40960;                       // (N+1)*128 bf16 (row N = zeros)
  ushort_t* h1   = hs + (size_t)128 * (N + 1);       // N*128 bf16 (h1, then h2)

  const int nChunks = (E + PLACE_CHUNK - 1) / PLACE_CHUNK;
  const int nPlace = nChunks * 4;        // 4 dst partitions per chunk
  const int Gb64 = (N + 63) / 64;        // GEMM1 blocks
  const int Gg128 = (N + 127) / 128;     // GEMM2/gate blocks
  const int quarterN = (N + 3) / 4;

  // K1: init (fill=0, Wt prep, zero hs row N)
  int initIds = Np + 40960 + 64;
  init_kernel<<<(initIds + 255) / 256, 256, 0, stream>>>(
      fill, W1, W2, Wg1, Wt, (uint_t*)(hs + (size_t)128 * N), Np);

  // K2: place (dst-partitioned, XCD-local) || GEMM1, interleaved 1:1
  int nPairs = nPlace > Gb64 ? nPlace : Gb64;
  place_gemm1_kernel<<<2 * nPairs, 256, 0, stream>>>(
      src, dst, fill, srcs_pad, E, x, Wt, hs, N, nPlace, Gb64, quarterN);

  // K3: aggregate1 (per-source dinv at gather time; writes dinv[])
  aggregate_ln_kernel<true><<<(N + 3) / 4, 256, 0, stream>>>(
      hs, fill, srcs_pad, dinv, b1, g1, be1, h1, N);
  // K4: GEMM2 (pre-scales output rows by dinv)
  gemm_mfma_kernel<128, true, false, false><<<Gg128, 256, 0, stream>>>(
      h1, Wt + 16384, nullptr, dinv, hs, N, nullptr, nullptr, nullptr);
  // K5: aggregate2 (rows pre-scaled; e = 1/0 only)
  aggregate_ln_kernel<false><<<(N + 3) / 4, 256, 0, stream>>>(
      hs, fill, srcs_pad, dinv, b2, g2, be2, h1, N);
  // K6: gate GEMM + fused dot
  gemm_mfma_kernel<64, false, true, true><<<Gg128, 256, 0, stream>>>(
      h1, Wt + 32768, bg1, nullptr, nullptr, N, Wg2, bg2, gatep);

  pool_partial_kernel<<<B * POOL_S, 256, 0, stream>>>(
      h1, gatep, bat, ppart, pstat, N);
  classify_kernel<<<B, 128, 0, stream>>>(ppart, pstat, Wc, bc, (float*)d_out);
}

// Round 3
// 382.810 us; speedup vs baseline: 1.0196x; 1.0196x over previous
//
#include <hip/hip_runtime.h>

// ---------------------------------------------------------------------------
// GCN pipeline (bf16 buffers, fp32 accumulation).
// R16 = R14 structure with place replaced by two-phase LDS binning (no
// per-edge global atomics):
//   K1   init: gcount=0, Wt=bf16(W^T), zero row N of hs     (1 dispatch)
//   K2   bin (pass A) || GEMM1 [1:1 roles]. Bin: per-block LDS histogram over
//        782 buckets (bucket = dst>>7), ONE global atomic per (block,bucket)
//        to reserve space (~153K atomics vs 1.6M), scatter packed
//        (src<<7)|dst_local into per-bucket lists. A block-bucket run (~10
//        words) is written within ~1us -> L2 write-combining works (R15
//        failed because row writes were spread over 90us across blocks).
//   K2b  build (pass B): block per bucket; LDS atomics resolve positions into
//        a 33KB staging tile; fill + srcs_pad rows flushed coalesced (int4).
//        Zero global atomics. Contract to aggregate unchanged.
//   K3   aggregate_ln1 -> h1  (wave/node; per-source dinv from fill[] at
//        gather time via fma; lanes >= count clamped to (s=N,e=0); writes dinv)
//   K4   GEMM2: hs2 = bf16((h1@W2)*dinv)  (hs overwritten, row N stays 0)
//   K5   aggregate_ln2 -> h2 (h1 buffer; pre-scaled rows, e=1/0)
//   K6   gate GEMM + fused dot -> gate[N]
//   K7   pool_partial (B*16), K8 classify (B)
// History: R14 387us (place 90 = global-atomic ceiling, aggregate 85 =
// random-gather fabric ceiling). R15 XCD-partitioned place FAILED (writes
// did not combine: wrong temporal window, 4x edge re-read not L3-absorbed).
// Buckets buffer (12.8MB) aliases h1 (dead until K3 writes it).
// ---------------------------------------------------------------------------

typedef unsigned short ushort_t;
typedef unsigned int uint_t;
typedef __attribute__((ext_vector_type(8))) short short8;   // 8 x bf16
typedef __attribute__((ext_vector_type(4))) float floatx4;  // MFMA acc

#define POOL_S 16
#define PAD_DEG 64      // padded CSR row stride (deg ~ Poisson(16); max ~45)
#define BW_SH 7         // bucket width shift: 128 nodes/bucket
#define BUCKET_W 128
#define NBMAX 1024      // allocated bucket counters (NB = ceil(N/128) = 782)
#define CAP 4096        // bucket capacity (mean 2047, sd ~45 -> 45 sd margin)
#define CHUNK 8192      // edges per bin block

__device__ inline ushort_t bf16_rn(float f) {
  uint_t u = __float_as_uint(f);
  u += 0x7fffu + ((u >> 16) & 1u);
  return (ushort_t)(u >> 16);
}
__device__ inline float bf16_lo(uint_t v) { return __uint_as_float(v << 16); }
__device__ inline float bf16_hi(uint_t v) { return __uint_as_float(v & 0xffff0000u); }
__device__ inline uint_t bf16_pack(float a, float b) {
  return (uint_t)bf16_rn(a) | ((uint_t)bf16_rn(b) << 16);
}

// ---------------- K1: init (gcount=0, Wt prep, zero hs row N) -------------
__global__ __launch_bounds__(256) void init_kernel(
    int* __restrict__ gcount, const float* __restrict__ W1,
    const float* __restrict__ W2, const float* __restrict__ Wg1,
    ushort_t* __restrict__ Wt, uint_t* __restrict__ hs_rowN) {
  int id = blockIdx.x * 256 + threadIdx.x;
  if (id < NBMAX) { gcount[id] = 0; return; }
  int id2 = id - NBMAX;
  if (id2 < 40960) {
    float v;
    if (id2 < 16384) {
      int n = id2 >> 7, k = id2 & 127;
      v = W1[k * 128 + n];
    } else if (id2 < 32768) {
      int i2 = id2 - 16384;
      int n = i2 >> 7, k = i2 & 127;
      v = W2[k * 128 + n];
    } else {
      int i2 = id2 - 32768;
      int n = i2 >> 7, k = i2 & 127;
      v = Wg1[k * 64 + n];
    }
    Wt[id2] = bf16_rn(v);
    return;
  }
  int id3 = id2 - 40960;
  if (id3 < 64) hs_rowN[id3] = 0;
}

// ---------------- GEMM tile body (K=128 fixed, Wt bf16 [n][128]) ----------
template <int TM, int NC, bool IN_F32, bool SCALE, bool BIASRELU, bool GATEDOT>
__device__ __forceinline__ void gemm_tile(
    const void* __restrict__ in, const ushort_t* __restrict__ Wt,
    const float* __restrict__ bias, const float* __restrict__ dinv,
    ushort_t* __restrict__ out, int M, int row0,
    const float* __restrict__ Wg2, const float* __restrict__ bg2,
    float* __restrict__ gate_out, short* As) {
  constexpr int CT = NC / 16;
  constexpr int RT = TM / 64;
  const int t = threadIdx.x;
#pragma unroll
  for (int i = 0; i < TM / 16; ++i) {
    int chunk = t + i * 256;
    int rr = chunk >> 4, c8 = (chunk & 15) * 8;
    int row = row0 + rr;
    short8 val = {0, 0, 0, 0, 0, 0, 0, 0};
    if (IN_F32) {
      const float* inf = (const float*)in;
      if (row < M) {
        float4 v0 = *(const float4*)(inf + (size_t)row * 128 + c8);
        float4 v1 = *(const float4*)(inf + (size_t)row * 128 + c8 + 4);
        val[0] = (short)bf16_rn(v0.x); val[1] = (short)bf16_rn(v0.y);
        val[2] = (short)bf16_rn(v0.z); val[3] = (short)bf16_rn(v0.w);
        val[4] = (short)bf16_rn(v1.x); val[5] = (short)bf16_rn(v1.y);
        val[6] = (short)bf16_rn(v1.z); val[7] = (short)bf16_rn(v1.w);
      }
    } else {
      const short* inb = (const short*)in;
      if (row < M) val = *(const short8*)(inb + (size_t)row * 128 + c8);
    }
    *(short8*)&As[rr * 136 + c8] = val;
  }
  __syncthreads();

  const int wave = t >> 6, lane = t & 63;
  const int m16 = lane & 15, quad = lane >> 4;
  floatx4 acc[RT][CT];
#pragma unroll
  for (int rt = 0; rt < RT; ++rt)
#pragma unroll
    for (int ct = 0; ct < CT; ++ct) acc[rt][ct] = (floatx4){0.f, 0.f, 0.f, 0.f};
#pragma unroll
  for (int ks = 0; ks < 4; ++ks) {
    int koff = ks * 32 + quad * 8;
    short8 a[RT];
#pragma unroll
    for (int rt = 0; rt < RT; ++rt)
      a[rt] = *(const short8*)&As[(wave * 16 + rt * 64 + m16) * 136 + koff];
#pragma unroll
    for (int ct = 0; ct < CT; ++ct) {
      short8 b = *(const short8*)((const short*)Wt + (size_t)(ct * 16 + m16) * 128 + koff);
#pragma unroll
      for (int rt = 0; rt < RT; ++rt)
        acc[rt][ct] = __builtin_amdgcn_mfma_f32_16x16x32_bf16(a[rt], b, acc[rt][ct], 0, 0, 0);
    }
  }

  float bv[CT];
  if (BIASRELU) {
#pragma unroll
    for (int ct = 0; ct < CT; ++ct) bv[ct] = bias[ct * 16 + m16];
  }

  if (GATEDOT) {
    float w2[CT];
#pragma unroll
    for (int ct = 0; ct < CT; ++ct) w2[ct] = Wg2[ct * 16 + m16];
    float bg2v = bg2[0];
#pragma unroll
    for (int rt = 0; rt < RT; ++rt) {
#pragma unroll
      for (int reg = 0; reg < 4; ++reg) {
        float p = 0.f;
#pragma unroll
        for (int ct = 0; ct < CT; ++ct)
          p += fmaxf(acc[rt][ct][reg] + bv[ct], 0.f) * w2[ct];
        p += __shfl_xor(p, 1);
        p += __shfl_xor(p, 2);
        p += __shfl_xor(p, 4);
        p += __shfl_xor(p, 8);
        if (m16 == 0) {
          int row = row0 + wave * 16 + rt * 64 + quad * 4 + reg;
          if (row < M) gate_out[row] = p + bg2v;
        }
      }
    }
    return;
  }

#pragma unroll
  for (int rt = 0; rt < RT; ++rt) {
#pragma unroll
    for (int reg = 0; reg < 4; ++reg) {
      int row = row0 + wave * 16 + rt * 64 + quad * 4 + reg;
      if (row < M) {
        float mult = SCALE ? dinv[row] : 1.f;
#pragma unroll
        for (int ct = 0; ct < CT; ++ct) {
          float v = acc[rt][ct][reg];
          if (BIASRELU) v = fmaxf(v + bv[ct], 0.f);
          else if (SCALE) v *= mult;
          out[(size_t)row * NC + ct * 16 + m16] = bf16_rn(v);
        }
      }
    }
  }
}

// ---------------- K2: bin (pass A, LDS histogram) || GEMM1 ----------------
__global__ __launch_bounds__(256) void bin_gemm1_kernel(
    const int* __restrict__ src, const int* __restrict__ dst,
    int* __restrict__ gcount, int* __restrict__ buckets, int E,
    const float* __restrict__ x, const ushort_t* __restrict__ Wt,
    ushort_t* __restrict__ hs, int M, int nBin, int nGemm) {
  __shared__ short As[64 * 136];   // GEMM role (17408 B)
  __shared__ int cntL[NBMAX];      // bin role: per-bucket histogram (4 KB)
  __shared__ int offL[NBMAX];      // bin role: global write cursor (4 KB)
  int b = blockIdx.x;
  int gi = b >> 1;
  if (b & 1) {
    if (gi < nGemm)
      gemm_tile<64, 128, true, false, false, false>(
          x, Wt, nullptr, nullptr, hs, M, gi * 64, nullptr, nullptr, nullptr, As);
    return;
  }
  if (gi < nBin) {
    const int t = threadIdx.x;
    const int base = gi * CHUNK;
    int c = E - base;
    if (c > CHUNK) c = CHUNK;
    for (int i = t; i < NBMAX; i += 256) cntL[i] = 0;
    __syncthreads();
    // histogram (LDS atomics only)
    for (int i = t; i < c; i += 256) {
      int d = dst[base + i];
      atomicAdd(&cntL[d >> BW_SH], 1);
    }
    __syncthreads();
    // one global reservation per non-empty (block,bucket)
    for (int i = t; i < NBMAX; i += 256) {
      int cn = cntL[i];
      offL[i] = cn ? atomicAdd(&gcount[i], cn) : 0;
    }
    __syncthreads();
    // scatter packed (src<<7)|dst_local; runs per bucket are contiguous and
    // written within ~1us by this block -> L2 combines sectors
    for (int i = t; i < c; i += 256) {
      int s = src[base + i];
      int d = dst[base + i];
      int bk = d >> BW_SH;
      int pos = atomicAdd(&offL[bk], 1);
      if (pos < CAP)
        buckets[(size_t)bk * CAP + pos] = (s << BW_SH) | (d & (BUCKET_W - 1));
    }
  }
}

// ---------------- K2b: build (pass B) -------------------------------------
// Block per bucket (128 nodes). LDS atomics resolve per-node positions into a
// staging tile; fill + srcs_pad rows flushed fully coalesced. No global
// atomics. Garbage beyond fillL[l] in a row is fine (aggregate clamps).
__global__ __launch_bounds__(256) void build_kernel(
    const int* __restrict__ gcount, const int* __restrict__ buckets,
    int* __restrict__ fill, int* __restrict__ srcs_pad, int N) {
  __shared__ int fillL[BUCKET_W];
  __shared__ alignas(16) int srcsL[BUCKET_W * PAD_DEG];  // 32 KB
  const int b = blockIdx.x, t = threadIdx.x;
  if (t < BUCKET_W) fillL[t] = 0;
  __syncthreads();
  int cnt = gcount[b];
  if (cnt > CAP) cnt = CAP;
  const int* bk = buckets + (size_t)b * CAP;
  for (int i = t; i < cnt; i += 256) {
    int v = bk[i];
    int local = v & (BUCKET_W - 1);
    int s = (int)(((uint_t)v) >> BW_SH);
    int p = atomicAdd(&fillL[local], 1);
    if (p < PAD_DEG) srcsL[local * PAD_DEG + p] = s;
  }
  __syncthreads();
  const int node0 = b << BW_SH;
  int width = N - node0;
  if (width <= 0) return;
  if (width > BUCKET_W) width = BUCKET_W;
  if (t < width) fill[node0 + t] = fillL[t];
  const int tot4 = (width * PAD_DEG) >> 2;
  int4* dstp = (int4*)(srcs_pad + (size_t)node0 * PAD_DEG);
  const int4* srcp = (const int4*)srcsL;
  for (int j = t; j < tot4; j += 256) dstp[j] = srcp[j];
}

// ---------------- standalone MFMA GEMM (GEMM2, gate) ----------------------
template <int NC, bool SCALE, bool BIASRELU, bool GATEDOT>
__global__ __launch_bounds__(256) void gemm_mfma_kernel(
    const ushort_t* __restrict__ in, const ushort_t* __restrict__ Wt,
    const float* __restrict__ bias, const float* __restrict__ dinv,
    ushort_t* __restrict__ out, int M,
    const float* __restrict__ Wg2, const float* __restrict__ bg2,
    float* __restrict__ gate_out) {
  __shared__ short As[128 * 136];
  gemm_tile<128, NC, false, SCALE, BIASRELU, GATEDOT>(
      in, Wt, bias, dinv, out, M, blockIdx.x * 128, Wg2, bg2, gate_out, As);
}

// ---------------- aggregate + LN + ReLU -----------------------------------
// wave per node; srcs row preloaded into one register; indices + per-edge
// scale factors broadcast via shfl. Lanes >= count are clamped in-register to
// (s=N, e=0): no sentinel padding needed, no OOB on garbage slots.
// PERSRC=true : gathered rows are raw (x@W1); scale each by dinv[s] computed
//               from fill[s] (L2-resident), self row by dv; writes dinv[n].
// PERSRC=false: gathered rows pre-scaled by GEMM2 epilogue; e = 1/0 only.
__device__ __forceinline__ void fma8(float* a, uint4 v, float e) {
  a[0] = fmaf(bf16_lo(v.x), e, a[0]); a[1] = fmaf(bf16_hi(v.x), e, a[1]);
  a[2] = fmaf(bf16_lo(v.y), e, a[2]); a[3] = fmaf(bf16_hi(v.y), e, a[3]);
  a[4] = fmaf(bf16_lo(v.z), e, a[4]); a[5] = fmaf(bf16_hi(v.z), e, a[5]);
  a[6] = fmaf(bf16_lo(v.w), e, a[6]); a[7] = fmaf(bf16_hi(v.w), e, a[7]);
}

template <bool PERSRC>
__global__ __launch_bounds__(256) void aggregate_ln_kernel(
    const ushort_t* __restrict__ hs, const int* __restrict__ fill,
    const int* __restrict__ srcs_pad, float* __restrict__ dinv,
    const float* __restrict__ bias, const float* __restrict__ gamma,
    const float* __restrict__ beta, ushort_t* __restrict__ out, int N) {
  int n = (blockIdx.x * 256 + threadIdx.x) >> 6;
  int lane = threadIdx.x & 63;
  if (n >= N) return;
  const int col = lane & 15, epar = lane >> 4;
  const uint4* hs4 = (const uint4*)hs;  // 16 uint4 per row; row N is zeros
  int sreg = srcs_pad[(size_t)n * PAD_DEG + lane];  // whole padded row
  int count = fill[n];
  if (count > PAD_DEG) count = PAD_DEG;
  const int K = (count + 3) & ~3;  // wave-uniform, multiple of 4
  float dv = rsqrtf((float)(count + 1));
  // per-lane clamp + scale precompute (predicated: garbage sreg never loads)
  int sc = N;
  float dreg = 0.f;
  if (lane < count) {
    sc = sreg;
    if (PERSRC) dreg = rsqrtf((float)(fill[sc] + 1));
    else        dreg = 1.f;
  }
  float a[8] = {0.f, 0.f, 0.f, 0.f, 0.f, 0.f, 0.f, 0.f};
  int i = epar;
  for (; i + 12 < K; i += 16) {  // 4 edges per lane in flight
    int s0 = __shfl(sc, i);       float e0 = __shfl(dreg, i);
    int s1 = __shfl(sc, i + 4);   float e1 = __shfl(dreg, i + 4);
    int s2 = __shfl(sc, i + 8);   float e2 = __shfl(dreg, i + 8);
    int s3 = __shfl(sc, i + 12);  float e3 = __shfl(dreg, i + 12);
    uint4 v0 = hs4[(size_t)s0 * 16 + col];
    uint4 v1 = hs4[(size_t)s1 * 16 + col];
    uint4 v2 = hs4[(size_t)s2 * 16 + col];
    uint4 v3 = hs4[(size_t)s3 * 16 + col];
    fma8(a, v0, e0); fma8(a, v1, e1); fma8(a, v2, e2); fma8(a, v3, e3);
  }
  for (; i < K; i += 4) {
    int s = __shfl(sc, i);
    float e = __shfl(dreg, i);
    uint4 v = hs4[(size_t)s * 16 + col];
    fma8(a, v, e);
  }
#pragma unroll
  for (int k = 0; k < 8; ++k) {
    a[k] += __shfl_xor(a[k], 16);
    a[k] += __shfl_xor(a[k], 32);
  }
  {
    uint4 sv = hs4[(size_t)n * 16 + col];
    fma8(a, sv, PERSRC ? dv : 1.f);  // self loop
  }
  if (PERSRC && lane == 0) dinv[n] = dv;  // for GEMM2 epilogue
  float4 b0 = *(const float4*)(bias + 8 * col);
  float4 b1 = *(const float4*)(bias + 8 * col + 4);
  float y[8];
  y[0] = a[0] * dv + b0.x; y[1] = a[1] * dv + b0.y;
  y[2] = a[2] * dv + b0.z; y[3] = a[3] * dv + b0.w;
  y[4] = a[4] * dv + b1.x; y[5] = a[5] * dv + b1.y;
  y[6] = a[6] * dv + b1.z; y[7] = a[7] * dv + b1.w;
  float s1 = 0.f, s2 = 0.f;
#pragma unroll
  for (int k = 0; k < 8; ++k) { s1 += y[k]; s2 += y[k] * y[k]; }
#pragma unroll
  for (int off = 1; off <= 8; off <<= 1) {
    s1 += __shfl_xor(s1, off);
    s2 += __shfl_xor(s2, off);
  }
  float mu = s1 * (1.f / 128.f);
  float var = s2 * (1.f / 128.f) - mu * mu;
  float rinv = rsqrtf(var + 1e-5f);
  float4 g0 = *(const float4*)(gamma + 8 * col);
  float4 g1 = *(const float4*)(gamma + 8 * col + 4);
  float4 e0 = *(const float4*)(beta + 8 * col);
  float4 e1 = *(const float4*)(beta + 8 * col + 4);
  float o[8];
  o[0] = fmaxf((y[0] - mu) * rinv * g0.x + e0.x, 0.f);
  o[1] = fmaxf((y[1] - mu) * rinv * g0.y + e0.y, 0.f);
  o[2] = fmaxf((y[2] - mu) * rinv * g0.z + e0.z, 0.f);
  o[3] = fmaxf((y[3] - mu) * rinv * g0.w + e0.w, 0.f);
  o[4] = fmaxf((y[4] - mu) * rinv * g1.x + e1.x, 0.f);
  o[5] = fmaxf((y[5] - mu) * rinv * g1.y + e1.y, 0.f);
  o[6] = fmaxf((y[6] - mu) * rinv * g1.z + e1.z, 0.f);
  o[7] = fmaxf((y[7] - mu) * rinv * g1.w + e1.w, 0.f);
  if (epar == 0) {
    uint4 pk;
    pk.x = bf16_pack(o[0], o[1]); pk.y = bf16_pack(o[2], o[3]);
    pk.z = bf16_pack(o[4], o[5]); pk.w = bf16_pack(o[6], o[7]);
    ((uint4*)out)[(size_t)n * 16 + col] = pk;
  }
}

// ---------------- pooling: local online-softmax partials + merge ----------
__device__ inline int lower_bound_i(const int* a, int n, int key) {
  int lo = 0, hi = n;
  while (lo < hi) {
    int mid = (lo + hi) >> 1;
    if (a[mid] < key) lo = mid + 1; else hi = mid;
  }
  return lo;
}

// K7: grid B*POOL_S. Local stats: m_k (max), d_k (sum exp), S_k[128].
__global__ __launch_bounds__(256) void pool_partial_kernel(
    const ushort_t* __restrict__ h2, const float* __restrict__ gate,
    const int* __restrict__ batch, float* __restrict__ partial,
    float2* __restrict__ pstat, int N) {
  int g = blockIdx.x / POOL_S, sub = blockIdx.x % POOL_S;
  int t = threadIdx.x;
  __shared__ float redx[256];
  __shared__ float redy[256];
  __shared__ float s_m;
  int lo = lower_bound_i(batch, N, g);
  int hi = lower_bound_i(batch, N, g + 1);
  int len = hi - lo;
  int chunk = (len + POOL_S - 1) / POOL_S;
  int a = lo + sub * chunk;
  int b = a + chunk < hi ? a + chunk : hi;
  float m = -3.4e38f;
  for (int i = a + t; i < b; i += 256) m = fmaxf(m, gate[i]);
  redx[t] = m;
  __syncthreads();
  for (int off = 128; off; off >>= 1) {
    if (t < off) redx[t] = fmaxf(redx[t], redx[t + off]);
    __syncthreads();
  }
  if (t == 0) s_m = redx[0];
  __syncthreads();
  float gmax = s_m;
  __syncthreads();
  float ssum = 0.f;
  for (int i = a + t; i < b; i += 256) ssum += expf(gate[i] - gmax);
  redx[t] = ssum;
  __syncthreads();
  for (int off = 128; off; off >>= 1) {
    if (t < off) redx[t] += redx[t + off];
    __syncthreads();
  }
  float denom = redx[0];
  __syncthreads();
  int p = t & 63, strm = t >> 6;
  const uint_t* h2u = (const uint_t*)h2;
  float accx = 0.f, accy = 0.f;
  int i = a + strm;
  for (; i + 8 <= b; i += 8) {
    float e0 = expf(gate[i] - gmax);
    float e1 = expf(gate[i + 4] - gmax);
    uint_t v0 = h2u[(size_t)i * 64 + p];
    uint_t v1 = h2u[(size_t)(i + 4) * 64 + p];
    accx += e0 * bf16_lo(v0) + e1 * bf16_lo(v1);
    accy += e0 * bf16_hi(v0) + e1 * bf16_hi(v1);
  }
  for (; i < b; i += 4) {
    float e = expf(gate[i] - gmax);
    uint_t v = h2u[(size_t)i * 64 + p];
    accx += e * bf16_lo(v);
    accy += e * bf16_hi(v);
  }
  redx[t] = accx;
  redy[t] = accy;
  __syncthreads();
  if (t < 64) {
    float px = redx[t] + redx[t + 64] + redx[t + 128] + redx[t + 192];
    float py = redy[t] + redy[t + 64] + redy[t + 128] + redy[t + 192];
    float* dstp = partial + (size_t)blockIdx.x * 128;
    dstp[2 * t] = px;
    dstp[2 * t + 1] = py;
  }
  if (t == 0) pstat[blockIdx.x] = make_float2(gmax, denom);
}

// K8: merge partials with exp(m_k - M) rescale, classifier
__global__ __launch_bounds__(128) void classify_kernel(
    const float* __restrict__ partial, const float2* __restrict__ pstat,
    const float* __restrict__ Wc, const float* __restrict__ bc,
    float* __restrict__ out) {
  int g = blockIdx.x, t = threadIdx.x;
  __shared__ float pooled[128];
  __shared__ float wgt[POOL_S];
  __shared__ float s_inv;
  if (t == 0) {
    float M = -3.4e38f;
    float2 st[POOL_S];
#pragma unroll
    for (int k = 0; k < POOL_S; ++k) {
      st[k] = pstat[g * POOL_S + k];
      M = fmaxf(M, st[k].x);
    }
    float total = 0.f;
#pragma unroll
    for (int k = 0; k < POOL_S; ++k) {
      float w = expf(st[k].x - M);
      wgt[k] = w;
      total += st[k].y * w;
    }
    s_inv = total > 0.f ? 1.f / total : 0.f;
  }
  __syncthreads();
  float inv = s_inv;
  float s = 0.f;
#pragma unroll
  for (int k = 0; k < POOL_S; ++k)
    s += partial[((size_t)g * POOL_S + k) * 128 + t] * wgt[k];
  pooled[t] = s * inv;
  __syncthreads();
  if (t < 16) {
    float o = bc[t];
    for (int ff = 0; ff < 128; ++ff) o = fmaf(pooled[ff], Wc[ff * 16 + t], o);
    out[g * 16 + t] = o;
  }
}

// ---------------- host launcher ----------------
extern "C" void kernel_launch(void* const* d_in, const int* in_sizes, int n_in,
                              void* d_out, int out_size, void* d_ws, size_t ws_size,
                              hipStream_t stream) {
  const float* x   = (const float*)d_in[0];
  const int*   ei  = (const int*)d_in[1];
  const int*   bat = (const int*)d_in[2];
  const float* W1  = (const float*)d_in[3];
  const float* b1  = (const float*)d_in[4];
  const float* g1  = (const float*)d_in[5];
  const float* be1 = (const float*)d_in[6];
  const float* W2  = (const float*)d_in[7];
  const float* b2  = (const float*)d_in[8];
  const float* g2  = (const float*)d_in[9];
  const float* be2 = (const float*)d_in[10];
  const float* Wg1 = (const float*)d_in[11];
  const float* bg1 = (const float*)d_in[12];
  const float* Wg2 = (const float*)d_in[13];
  const float* bg2 = (const float*)d_in[14];
  const float* Wc  = (const float*)d_in[15];
  const float* bc  = (const float*)d_in[16];

  const int N = in_sizes[0] / 128;
  const int E = in_sizes[1] / 2;
  const int B = out_size / 16;
  const int* src = ei;
  const int* dst = ei + E;

  const int Np = (N + 3) & ~3;

  int* fill      = (int*)d_ws;                       // Np
  float* dinv    = (float*)(fill + Np);              // Np
  float* gatep   = dinv + Np;                        // Np
  int* gcount    = (int*)(gatep + Np);               // NBMAX
  float2* pstat  = (float2*)(gcount + NBMAX);        // B*POOL_S
  float* ppart   = (float*)(pstat + B * POOL_S);     // B*POOL_S*128
  int* srcs_pad  = (int*)(ppart + (size_t)B * POOL_S * 128);  // N*PAD_DEG
  ushort_t* Wt   = (ushort_t*)(srcs_pad + (size_t)N * PAD_DEG);  // 40960
  ushort_t* hs   = Wt + 40960;                       // (N+1)*128 bf16 (row N = zeros)
  ushort_t* h1   = hs + (size_t)128 * (N + 1);       // N*128 bf16 (h1, then h2)
  int* buckets   = (int*)h1;  // alias: NB*CAP*4 = 12.8MB < 25.6MB; dead by K3

  const int NB = (N + BUCKET_W - 1) >> BW_SH;   // 782
  const int nBin = (E + CHUNK - 1) / CHUNK;     // 196
  const int Gb64 = (N + 63) / 64;               // GEMM1 blocks
  const int Gg128 = (N + 127) / 128;            // GEMM2/gate blocks

  // K1: init (gcount=0, Wt prep, zero hs row N)
  int initIds = NBMAX + 40960 + 64;
  init_kernel<<<(initIds + 255) / 256, 256, 0, stream>>>(
      gcount, W1, W2, Wg1, Wt, (uint_t*)(hs + (size_t)128 * N));

  // K2: bin (pass A) || GEMM1, interleaved 1:1
  int nPairs = nBin > Gb64 ? nBin : Gb64;
  bin_gemm1_kernel<<<2 * nPairs, 256, 0, stream>>>(
      src, dst, gcount, buckets, E, x, Wt, hs, N, nBin, Gb64);

  // K2b: build (pass B): bucket lists -> fill + srcs_pad
  build_kernel<<<NB, 256, 0, stream>>>(gcount, buckets, fill, srcs_pad, N);

  // K3: aggregate1 (per-source dinv at gather time; writes dinv[])
  aggregate_ln_kernel<true><<<(N + 3) / 4, 256, 0, stream>>>(
      hs, fill, srcs_pad, dinv, b1, g1, be1, h1, N);
  // K4: GEMM2 (pre-scales output rows by dinv)
  gemm_mfma_kernel<128, true, false, false><<<Gg128, 256, 0, stream>>>(
      h1, Wt + 16384, nullptr, dinv, hs, N, nullptr, nullptr, nullptr);
  // K5: aggregate2 (rows pre-scaled; e = 1/0 only)
  aggregate_ln_kernel<false><<<(N + 3) / 4, 256, 0, stream>>>(
      hs, fill, srcs_pad, dinv, b2, g2, be2, h1, N);
  // K6: gate GEMM + fused dot
  gemm_mfma_kernel<64, false, true, true><<<Gg128, 256, 0, stream>>>(
      h1, Wt + 32768, bg1, nullptr, nullptr, N, Wg2, bg2, gatep);

  pool_partial_kernel<<<B * POOL_S, 256, 0, stream>>>(
      h1, gatep, bat, ppart, pstat, N);
  classify_kernel<<<B, 128, 0, stream>>>(ppart, pstat, Wc, bc, (float*)d_out);
}

// Round 4
// 378.330 us; speedup vs baseline: 1.0317x; 1.0118x over previous
//
#include <hip/hip_runtime.h>

// ---------------------------------------------------------------------------
// GCN pipeline (bf16 buffers, fp32 accumulation).
// R17 = R16 + int4-vectorized edge streams in bin + build (latency-chain fix):
//   K1   init: gcount=0, Wt=bf16(W^T), zero row N of hs     (1 dispatch)
//   K2   bin (pass A) || GEMM1 [1:1 roles]. Bin: per-block LDS histogram over
//        782 buckets (bucket = dst>>7), ONE global atomic per (block,bucket)
//        to reserve space, scatter packed (src<<7)|dst_local into per-bucket
//        lists. Edge loads are int4 (4 edges/instr, 4-deep ILP): R16 counters
//        showed 2900 cy/iteration = scalar-load latency serialization, with
//        HBM 15% / VALU 5% / Mfma 1.5% (nothing saturated).
//   K2b  build (pass B): block per bucket; LDS atomics resolve positions into
//        a 33KB staging tile; fill + srcs_pad rows flushed coalesced (int4).
//        Bucket-list reads int4-vectorized.
//   K3   aggregate_ln1 -> h1  (wave/node; per-source dinv from fill[] at
//        gather time via fma; lanes >= count clamped to (s=N,e=0); writes dinv)
//   K4   GEMM2: hs2 = bf16((h1@W2)*dinv)  (hs overwritten, row N stays 0)
//   K5   aggregate_ln2 -> h2 (h1 buffer; pre-scaled rows, e=1/0)
//   K6   gate GEMM + fused dot -> gate[N]
//   K7   pool_partial (B*16), K8 classify (B)
// History: R14 387us (place 90 = per-edge global atomics). R15 XCD-partition
// FAILED (wrong temporal window). R16 two-phase binning: WRITE 112->57MB
// (temporally-local runs DO combine), top dispatch 90->77us.
// Buckets buffer (12.8MB) aliases h1 (dead until K3 writes it).
// ---------------------------------------------------------------------------

typedef unsigned short ushort_t;
typedef unsigned int uint_t;
typedef __attribute__((ext_vector_type(8))) short short8;   // 8 x bf16
typedef __attribute__((ext_vector_type(4))) float floatx4;  // MFMA acc

#define POOL_S 16
#define PAD_DEG 64      // padded CSR row stride (deg ~ Poisson(16); max ~45)
#define BW_SH 7         // bucket width shift: 128 nodes/bucket
#define BUCKET_W 128
#define NBMAX 1024      // allocated bucket counters (NB = ceil(N/128) = 782)
#define CAP 4096        // bucket capacity (mean 2047, sd ~45 -> 45 sd margin)
#define CHUNK 8192      // edges per bin block

__device__ inline ushort_t bf16_rn(float f) {
  uint_t u = __float_as_uint(f);
  u += 0x7fffu + ((u >> 16) & 1u);
  return (ushort_t)(u >> 16);
}
__device__ inline float bf16_lo(uint_t v) { return __uint_as_float(v << 16); }
__device__ inline float bf16_hi(uint_t v) { return __uint_as_float(v & 0xffff0000u); }
__device__ inline uint_t bf16_pack(float a, float b) {
  return (uint_t)bf16_rn(a) | ((uint_t)bf16_rn(b) << 16);
}

// ---------------- K1: init (gcount=0, Wt prep, zero hs row N) -------------
__global__ __launch_bounds__(256) void init_kernel(
    int* __restrict__ gcount, const float* __restrict__ W1,
    const float* __restrict__ W2, const float* __restrict__ Wg1,
    ushort_t* __restrict__ Wt, uint_t* __restrict__ hs_rowN) {
  int id = blockIdx.x * 256 + threadIdx.x;
  if (id < NBMAX) { gcount[id] = 0; return; }
  int id2 = id - NBMAX;
  if (id2 < 40960) {
    float v;
    if (id2 < 16384) {
      int n = id2 >> 7, k = id2 & 127;
      v = W1[k * 128 + n];
    } else if (id2 < 32768) {
      int i2 = id2 - 16384;
      int n = i2 >> 7, k = i2 & 127;
      v = W2[k * 128 + n];
    } else {
      int i2 = id2 - 32768;
      int n = i2 >> 7, k = i2 & 127;
      v = Wg1[k * 64 + n];
    }
    Wt[id2] = bf16_rn(v);
    return;
  }
  int id3 = id2 - 40960;
  if (id3 < 64) hs_rowN[id3] = 0;
}

// ---------------- GEMM tile body (K=128 fixed, Wt bf16 [n][128]) ----------
template <int TM, int NC, bool IN_F32, bool SCALE, bool BIASRELU, bool GATEDOT>
__device__ __forceinline__ void gemm_tile(
    const void* __restrict__ in, const ushort_t* __restrict__ Wt,
    const float* __restrict__ bias, const float* __restrict__ dinv,
    ushort_t* __restrict__ out, int M, int row0,
    const float* __restrict__ Wg2, const float* __restrict__ bg2,
    float* __restrict__ gate_out, short* As) {
  constexpr int CT = NC / 16;
  constexpr int RT = TM / 64;
  const int t = threadIdx.x;
#pragma unroll
  for (int i = 0; i < TM / 16; ++i) {
    int chunk = t + i * 256;
    int rr = chunk >> 4, c8 = (chunk & 15) * 8;
    int row = row0 + rr;
    short8 val = {0, 0, 0, 0, 0, 0, 0, 0};
    if (IN_F32) {
      const float* inf = (const float*)in;
      if (row < M) {
        float4 v0 = *(const float4*)(inf + (size_t)row * 128 + c8);
        float4 v1 = *(const float4*)(inf + (size_t)row * 128 + c8 + 4);
        val[0] = (short)bf16_rn(v0.x); val[1] = (short)bf16_rn(v0.y);
        val[2] = (short)bf16_rn(v0.z); val[3] = (short)bf16_rn(v0.w);
        val[4] = (short)bf16_rn(v1.x); val[5] = (short)bf16_rn(v1.y);
        val[6] = (short)bf16_rn(v1.z); val[7] = (short)bf16_rn(v1.w);
      }
    } else {
      const short* inb = (const short*)in;
      if (row < M) val = *(const short8*)(inb + (size_t)row * 128 + c8);
    }
    *(short8*)&As[rr * 136 + c8] = val;
  }
  __syncthreads();

  const int wave = t >> 6, lane = t & 63;
  const int m16 = lane & 15, quad = lane >> 4;
  floatx4 acc[RT][CT];
#pragma unroll
  for (int rt = 0; rt < RT; ++rt)
#pragma unroll
    for (int ct = 0; ct < CT; ++ct) acc[rt][ct] = (floatx4){0.f, 0.f, 0.f, 0.f};
#pragma unroll
  for (int ks = 0; ks < 4; ++ks) {
    int koff = ks * 32 + quad * 8;
    short8 a[RT];
#pragma unroll
    for (int rt = 0; rt < RT; ++rt)
      a[rt] = *(const short8*)&As[(wave * 16 + rt * 64 + m16) * 136 + koff];
#pragma unroll
    for (int ct = 0; ct < CT; ++ct) {
      short8 b = *(const short8*)((const short*)Wt + (size_t)(ct * 16 + m16) * 128 + koff);
#pragma unroll
      for (int rt = 0; rt < RT; ++rt)
        acc[rt][ct] = __builtin_amdgcn_mfma_f32_16x16x32_bf16(a[rt], b, acc[rt][ct], 0, 0, 0);
    }
  }

  float bv[CT];
  if (BIASRELU) {
#pragma unroll
    for (int ct = 0; ct < CT; ++ct) bv[ct] = bias[ct * 16 + m16];
  }

  if (GATEDOT) {
    float w2[CT];
#pragma unroll
    for (int ct = 0; ct < CT; ++ct) w2[ct] = Wg2[ct * 16 + m16];
    float bg2v = bg2[0];
#pragma unroll
    for (int rt = 0; rt < RT; ++rt) {
#pragma unroll
      for (int reg = 0; reg < 4; ++reg) {
        float p = 0.f;
#pragma unroll
        for (int ct = 0; ct < CT; ++ct)
          p += fmaxf(acc[rt][ct][reg] + bv[ct], 0.f) * w2[ct];
        p += __shfl_xor(p, 1);
        p += __shfl_xor(p, 2);
        p += __shfl_xor(p, 4);
        p += __shfl_xor(p, 8);
        if (m16 == 0) {
          int row = row0 + wave * 16 + rt * 64 + quad * 4 + reg;
          if (row < M) gate_out[row] = p + bg2v;
        }
      }
    }
    return;
  }

#pragma unroll
  for (int rt = 0; rt < RT; ++rt) {
#pragma unroll
    for (int reg = 0; reg < 4; ++reg) {
      int row = row0 + wave * 16 + rt * 64 + quad * 4 + reg;
      if (row < M) {
        float mult = SCALE ? dinv[row] : 1.f;
#pragma unroll
        for (int ct = 0; ct < CT; ++ct) {
          float v = acc[rt][ct][reg];
          if (BIASRELU) v = fmaxf(v + bv[ct], 0.f);
          else if (SCALE) v *= mult;
          out[(size_t)row * NC + ct * 16 + m16] = bf16_rn(v);
        }
      }
    }
  }
}

// ---------------- K2: bin (pass A, LDS histogram) || GEMM1 ----------------
__global__ __launch_bounds__(256) void bin_gemm1_kernel(
    const int* __restrict__ src, const int* __restrict__ dst,
    int* __restrict__ gcount, int* __restrict__ buckets, int E,
    const float* __restrict__ x, const ushort_t* __restrict__ Wt,
    ushort_t* __restrict__ hs, int M, int nBin, int nGemm) {
  __shared__ short As[64 * 136];   // GEMM role (17408 B)
  __shared__ int cntL[NBMAX];      // bin role: per-bucket histogram (4 KB)
  __shared__ int offL[NBMAX];      // bin role: global write cursor (4 KB)
  int b = blockIdx.x;
  int gi = b >> 1;
  if (b & 1) {
    if (gi < nGemm)
      gemm_tile<64, 128, true, false, false, false>(
          x, Wt, nullptr, nullptr, hs, M, gi * 64, nullptr, nullptr, nullptr, As);
    return;
  }
  if (gi < nBin) {
    const int t = threadIdx.x;
    const int base = gi * CHUNK;
    int c = E - base;
    if (c > CHUNK) c = CHUNK;
    const int cv = c & ~3;  // int4-vector body covers exactly [0, cv)
    for (int i = t; i < NBMAX; i += 256) cntL[i] = 0;
    __syncthreads();
    // histogram (LDS atomics only); int4 edge loads, 4-deep ILP
    for (int i = t * 4; i + 3 < c; i += 1024) {
      int4 d4 = *(const int4*)(dst + base + i);
      atomicAdd(&cntL[d4.x >> BW_SH], 1);
      atomicAdd(&cntL[d4.y >> BW_SH], 1);
      atomicAdd(&cntL[d4.z >> BW_SH], 1);
      atomicAdd(&cntL[d4.w >> BW_SH], 1);
    }
    for (int i = cv + t; i < c; i += 256)
      atomicAdd(&cntL[dst[base + i] >> BW_SH], 1);
    __syncthreads();
    // one global reservation per non-empty (block,bucket)
    for (int i = t; i < NBMAX; i += 256) {
      int cn = cntL[i];
      offL[i] = cn ? atomicAdd(&gcount[i], cn) : 0;
    }
    __syncthreads();
    // scatter packed (src<<7)|dst_local; int4 edge loads. A block-bucket run
    // (~10 words) is written within ~1us -> L2 write-combining works.
    for (int i = t * 4; i + 3 < c; i += 1024) {
      int4 d4 = *(const int4*)(dst + base + i);
      int4 s4 = *(const int4*)(src + base + i);
      int bk0 = d4.x >> BW_SH, bk1 = d4.y >> BW_SH;
      int bk2 = d4.z >> BW_SH, bk3 = d4.w >> BW_SH;
      int p0 = atomicAdd(&offL[bk0], 1);
      int p1 = atomicAdd(&offL[bk1], 1);
      int p2 = atomicAdd(&offL[bk2], 1);
      int p3 = atomicAdd(&offL[bk3], 1);
      if (p0 < CAP)
        buckets[(size_t)bk0 * CAP + p0] = (s4.x << BW_SH) | (d4.x & (BUCKET_W - 1));
      if (p1 < CAP)
        buckets[(size_t)bk1 * CAP + p1] = (s4.y << BW_SH) | (d4.y & (BUCKET_W - 1));
      if (p2 < CAP)
        buckets[(size_t)bk2 * CAP + p2] = (s4.z << BW_SH) | (d4.z & (BUCKET_W - 1));
      if (p3 < CAP)
        buckets[(size_t)bk3 * CAP + p3] = (s4.w << BW_SH) | (d4.w & (BUCKET_W - 1));
    }
    for (int i = cv + t; i < c; i += 256) {
      int s = src[base + i];
      int d = dst[base + i];
      int bk = d >> BW_SH;
      int pos = atomicAdd(&offL[bk], 1);
      if (pos < CAP)
        buckets[(size_t)bk * CAP + pos] = (s << BW_SH) | (d & (BUCKET_W - 1));
    }
  }
}

// ---------------- K2b: build (pass B) -------------------------------------
// Block per bucket (128 nodes). LDS atomics resolve per-node positions into a
// staging tile; fill + srcs_pad rows flushed fully coalesced. No global
// atomics. Garbage beyond fillL[l] in a row is fine (aggregate clamps).
__global__ __launch_bounds__(256) void build_kernel(
    const int* __restrict__ gcount, const int* __restrict__ buckets,
    int* __restrict__ fill, int* __restrict__ srcs_pad, int N) {
  __shared__ int fillL[BUCKET_W];
  __shared__ alignas(16) int srcsL[BUCKET_W * PAD_DEG];  // 32 KB
  const int b = blockIdx.x, t = threadIdx.x;
  if (t < BUCKET_W) fillL[t] = 0;
  __syncthreads();
  int cnt = gcount[b];
  if (cnt > CAP) cnt = CAP;
  const int cv = cnt & ~3;
  const int* bk = buckets + (size_t)b * CAP;
  for (int i = t * 4; i + 3 < cnt; i += 1024) {
    int4 v4 = *(const int4*)(bk + i);
#pragma unroll
    for (int j = 0; j < 4; ++j) {
      int v = (j == 0) ? v4.x : (j == 1) ? v4.y : (j == 2) ? v4.z : v4.w;
      int local = v & (BUCKET_W - 1);
      int s = (int)(((uint_t)v) >> BW_SH);
      int p = atomicAdd(&fillL[local], 1);
      if (p < PAD_DEG) srcsL[local * PAD_DEG + p] = s;
    }
  }
  for (int i = cv + t; i < cnt; i += 256) {
    int v = bk[i];
    int local = v & (BUCKET_W - 1);
    int s = (int)(((uint_t)v) >> BW_SH);
    int p = atomicAdd(&fillL[local], 1);
    if (p < PAD_DEG) srcsL[local * PAD_DEG + p] = s;
  }
  __syncthreads();
  const int node0 = b << BW_SH;
  int width = N - node0;
  if (width <= 0) return;
  if (width > BUCKET_W) width = BUCKET_W;
  if (t < width) fill[node0 + t] = fillL[t];
  const int tot4 = (width * PAD_DEG) >> 2;
  int4* dstp = (int4*)(srcs_pad + (size_t)node0 * PAD_DEG);
  const int4* srcp = (const int4*)srcsL;
  for (int j = t; j < tot4; j += 256) dstp[j] = srcp[j];
}

// ---------------- standalone MFMA GEMM (GEMM2, gate) ----------------------
template <int NC, bool SCALE, bool BIASRELU, bool GATEDOT>
__global__ __launch_bounds__(256) void gemm_mfma_kernel(
    const ushort_t* __restrict__ in, const ushort_t* __restrict__ Wt,
    const float* __restrict__ bias, const float* __restrict__ dinv,
    ushort_t* __restrict__ out, int M,
    const float* __restrict__ Wg2, const float* __restrict__ bg2,
    float* __restrict__ gate_out) {
  __shared__ short As[128 * 136];
  gemm_tile<128, NC, false, SCALE, BIASRELU, GATEDOT>(
      in, Wt, bias, dinv, out, M, blockIdx.x * 128, Wg2, bg2, gate_out, As);
}

// ---------------- aggregate + LN + ReLU -----------------------------------
// wave per node; srcs row preloaded into one register; indices + per-edge
// scale factors broadcast via shfl. Lanes >= count are clamped in-register to
// (s=N, e=0): no sentinel padding needed, no OOB on garbage slots.
// PERSRC=true : gathered rows are raw (x@W1); scale each by dinv[s] computed
//               from fill[s] (L2-resident), self row by dv; writes dinv[n].
// PERSRC=false: gathered rows pre-scaled by GEMM2 epilogue; e = 1/0 only.
__device__ __forceinline__ void fma8(float* a, uint4 v, float e) {
  a[0] = fmaf(bf16_lo(v.x), e, a[0]); a[1] = fmaf(bf16_hi(v.x), e, a[1]);
  a[2] = fmaf(bf16_lo(v.y), e, a[2]); a[3] = fmaf(bf16_hi(v.y), e, a[3]);
  a[4] = fmaf(bf16_lo(v.z), e, a[4]); a[5] = fmaf(bf16_hi(v.z), e, a[5]);
  a[6] = fmaf(bf16_lo(v.w), e, a[6]); a[7] = fmaf(bf16_hi(v.w), e, a[7]);
}

template <bool PERSRC>
__global__ __launch_bounds__(256) void aggregate_ln_kernel(
    const ushort_t* __restrict__ hs, const int* __restrict__ fill,
    const int* __restrict__ srcs_pad, float* __restrict__ dinv,
    const float* __restrict__ bias, const float* __restrict__ gamma,
    const float* __restrict__ beta, ushort_t* __restrict__ out, int N) {
  int n = (blockIdx.x * 256 + threadIdx.x) >> 6;
  int lane = threadIdx.x & 63;
  if (n >= N) return;
  const int col = lane & 15, epar = lane >> 4;
  const uint4* hs4 = (const uint4*)hs;  // 16 uint4 per row; row N is zeros
  int sreg = srcs_pad[(size_t)n * PAD_DEG + lane];  // whole padded row
  int count = fill[n];
  if (count > PAD_DEG) count = PAD_DEG;
  const int K = (count + 3) & ~3;  // wave-uniform, multiple of 4
  float dv = rsqrtf((float)(count + 1));
  // per-lane clamp + scale precompute (predicated: garbage sreg never loads)
  int sc = N;
  float dreg = 0.f;
  if (lane < count) {
    sc = sreg;
    if (PERSRC) dreg = rsqrtf((float)(fill[sc] + 1));
    else        dreg = 1.f;
  }
  float a[8] = {0.f, 0.f, 0.f, 0.f, 0.f, 0.f, 0.f, 0.f};
  int i = epar;
  for (; i + 12 < K; i += 16) {  // 4 edges per lane in flight
    int s0 = __shfl(sc, i);       float e0 = __shfl(dreg, i);
    int s1 = __shfl(sc, i + 4);   float e1 = __shfl(dreg, i + 4);
    int s2 = __shfl(sc, i + 8);   float e2 = __shfl(dreg, i + 8);
    int s3 = __shfl(sc, i + 12);  float e3 = __shfl(dreg, i + 12);
    uint4 v0 = hs4[(size_t)s0 * 16 + col];
    uint4 v1 = hs4[(size_t)s1 * 16 + col];
    uint4 v2 = hs4[(size_t)s2 * 16 + col];
    uint4 v3 = hs4[(size_t)s3 * 16 + col];
    fma8(a, v0, e0); fma8(a, v1, e1); fma8(a, v2, e2); fma8(a, v3, e3);
  }
  for (; i < K; i += 4) {
    int s = __shfl(sc, i);
    float e = __shfl(dreg, i);
    uint4 v = hs4[(size_t)s * 16 + col];
    fma8(a, v, e);
  }
#pragma unroll
  for (int k = 0; k < 8; ++k) {
    a[k] += __shfl_xor(a[k], 16);
    a[k] += __shfl_xor(a[k], 32);
  }
  {
    uint4 sv = hs4[(size_t)n * 16 + col];
    fma8(a, sv, PERSRC ? dv : 1.f);  // self loop
  }
  if (PERSRC && lane == 0) dinv[n] = dv;  // for GEMM2 epilogue
  float4 b0 = *(const float4*)(bias + 8 * col);
  float4 b1 = *(const float4*)(bias + 8 * col + 4);
  float y[8];
  y[0] = a[0] * dv + b0.x; y[1] = a[1] * dv + b0.y;
  y[2] = a[2] * dv + b0.z; y[3] = a[3] * dv + b0.w;
  y[4] = a[4] * dv + b1.x; y[5] = a[5] * dv + b1.y;
  y[6] = a[6] * dv + b1.z; y[7] = a[7] * dv + b1.w;
  float s1 = 0.f, s2 = 0.f;
#pragma unroll
  for (int k = 0; k < 8; ++k) { s1 += y[k]; s2 += y[k] * y[k]; }
#pragma unroll
  for (int off = 1; off <= 8; off <<= 1) {
    s1 += __shfl_xor(s1, off);
    s2 += __shfl_xor(s2, off);
  }
  float mu = s1 * (1.f / 128.f);
  float var = s2 * (1.f / 128.f) - mu * mu;
  float rinv = rsqrtf(var + 1e-5f);
  float4 g0 = *(const float4*)(gamma + 8 * col);
  float4 g1 = *(const float4*)(gamma + 8 * col + 4);
  float4 e0 = *(const float4*)(beta + 8 * col);
  float4 e1 = *(const float4*)(beta + 8 * col + 4);
  float o[8];
  o[0] = fmaxf((y[0] - mu) * rinv * g0.x + e0.x, 0.f);
  o[1] = fmaxf((y[1] - mu) * rinv * g0.y + e0.y, 0.f);
  o[2] = fmaxf((y[2] - mu) * rinv * g0.z + e0.z, 0.f);
  o[3] = fmaxf((y[3] - mu) * rinv * g0.w + e0.w, 0.f);
  o[4] = fmaxf((y[4] - mu) * rinv * g1.x + e1.x, 0.f);
  o[5] = fmaxf((y[5] - mu) * rinv * g1.y + e1.y, 0.f);
  o[6] = fmaxf((y[6] - mu) * rinv * g1.z + e1.z, 0.f);
  o[7] = fmaxf((y[7] - mu) * rinv * g1.w + e1.w, 0.f);
  if (epar == 0) {
    uint4 pk;
    pk.x = bf16_pack(o[0], o[1]); pk.y = bf16_pack(o[2], o[3]);
    pk.z = bf16_pack(o[4], o[5]); pk.w = bf16_pack(o[6], o[7]);
    ((uint4*)out)[(size_t)n * 16 + col] = pk;
  }
}

// ---------------- pooling: local online-softmax partials + merge ----------
__device__ inline int lower_bound_i(const int* a, int n, int key) {
  int lo = 0, hi = n;
  while (lo < hi) {
    int mid = (lo + hi) >> 1;
    if (a[mid] < key) lo = mid + 1; else hi = mid;
  }
  return lo;
}

// K7: grid B*POOL_S. Local stats: m_k (max), d_k (sum exp), S_k[128].
__global__ __launch_bounds__(256) void pool_partial_kernel(
    const ushort_t* __restrict__ h2, const float* __restrict__ gate,
    const int* __restrict__ batch, float* __restrict__ partial,
    float2* __restrict__ pstat, int N) {
  int g = blockIdx.x / POOL_S, sub = blockIdx.x % POOL_S;
  int t = threadIdx.x;
  __shared__ float redx[256];
  __shared__ float redy[256];
  __shared__ float s_m;
  int lo = lower_bound_i(batch, N, g);
  int hi = lower_bound_i(batch, N, g + 1);
  int len = hi - lo;
  int chunk = (len + POOL_S - 1) / POOL_S;
  int a = lo + sub * chunk;
  int b = a + chunk < hi ? a + chunk : hi;
  float m = -3.4e38f;
  for (int i = a + t; i < b; i += 256) m = fmaxf(m, gate[i]);
  redx[t] = m;
  __syncthreads();
  for (int off = 128; off; off >>= 1) {
    if (t < off) redx[t] = fmaxf(redx[t], redx[t + off]);
    __syncthreads();
  }
  if (t == 0) s_m = redx[0];
  __syncthreads();
  float gmax = s_m;
  __syncthreads();
  float ssum = 0.f;
  for (int i = a + t; i < b; i += 256) ssum += expf(gate[i] - gmax);
  redx[t] = ssum;
  __syncthreads();
  for (int off = 128; off; off >>= 1) {
    if (t < off) redx[t] += redx[t + off];
    __syncthreads();
  }
  float denom = redx[0];
  __syncthreads();
  int p = t & 63, strm = t >> 6;
  const uint_t* h2u = (const uint_t*)h2;
  float accx = 0.f, accy = 0.f;
  int i = a + strm;
  for (; i + 8 <= b; i += 8) {
    float e0 = expf(gate[i] - gmax);
    float e1 = expf(gate[i + 4] - gmax);
    uint_t v0 = h2u[(size_t)i * 64 + p];
    uint_t v1 = h2u[(size_t)(i + 4) * 64 + p];
    accx += e0 * bf16_lo(v0) + e1 * bf16_lo(v1);
    accy += e0 * bf16_hi(v0) + e1 * bf16_hi(v1);
  }
  for (; i < b; i += 4) {
    float e = expf(gate[i] - gmax);
    uint_t v = h2u[(size_t)i * 64 + p];
    accx += e * bf16_lo(v);
    accy += e * bf16_hi(v);
  }
  redx[t] = accx;
  redy[t] = accy;
  __syncthreads();
  if (t < 64) {
    float px = redx[t] + redx[t + 64] + redx[t + 128] + redx[t + 192];
    float py = redy[t] + redy[t + 64] + redy[t + 128] + redy[t + 192];
    float* dstp = partial + (size_t)blockIdx.x * 128;
    dstp[2 * t] = px;
    dstp[2 * t + 1] = py;
  }
  if (t == 0) pstat[blockIdx.x] = make_float2(gmax, denom);
}

// K8: merge partials with exp(m_k - M) rescale, classifier
__global__ __launch_bounds__(128) void classify_kernel(
    const float* __restrict__ partial, const float2* __restrict__ pstat,
    const float* __restrict__ Wc, const float* __restrict__ bc,
    float* __restrict__ out) {
  int g = blockIdx.x, t = threadIdx.x;
  __shared__ float pooled[128];
  __shared__ float wgt[POOL_S];
  __shared__ float s_inv;
  if (t == 0) {
    float M = -3.4e38f;
    float2 st[POOL_S];
#pragma unroll
    for (int k = 0; k < POOL_S; ++k) {
      st[k] = pstat[g * POOL_S + k];
      M = fmaxf(M, st[k].x);
    }
    float total = 0.f;
#pragma unroll
    for (int k = 0; k < POOL_S; ++k) {
      float w = expf(st[k].x - M);
      wgt[k] = w;
      total += st[k].y * w;
    }
    s_inv = total > 0.f ? 1.f / total : 0.f;
  }
  __syncthreads();
  float inv = s_inv;
  float s = 0.f;
#pragma unroll
  for (int k = 0; k < POOL_S; ++k)
    s += partial[((size_t)g * POOL_S + k) * 128 + t] * wgt[k];
  pooled[t] = s * inv;
  __syncthreads();
  if (t < 16) {
    float o = bc[t];
    for (int ff = 0; ff < 128; ++ff) o = fmaf(pooled[ff], Wc[ff * 16 + t], o);
    out[g * 16 + t] = o;
  }
}

// ---------------- host launcher ----------------
extern "C" void kernel_launch(void* const* d_in, const int* in_sizes, int n_in,
                              void* d_out, int out_size, void* d_ws, size_t ws_size,
                              hipStream_t stream) {
  const float* x   = (const float*)d_in[0];
  const int*   ei  = (const int*)d_in[1];
  const int*   bat = (const int*)d_in[2];
  const float* W1  = (const float*)d_in[3];
  const float* b1  = (const float*)d_in[4];
  const float* g1  = (const float*)d_in[5];
  const float* be1 = (const float*)d_in[6];
  const float* W2  = (const float*)d_in[7];
  const float* b2  = (const float*)d_in[8];
  const float* g2  = (const float*)d_in[9];
  const float* be2 = (const float*)d_in[10];
  const float* Wg1 = (const float*)d_in[11];
  const float* bg1 = (const float*)d_in[12];
  const float* Wg2 = (const float*)d_in[13];
  const float* bg2 = (const float*)d_in[14];
  const float* Wc  = (const float*)d_in[15];
  const float* bc  = (const float*)d_in[16];

  const int N = in_sizes[0] / 128;
  const int E = in_sizes[1] / 2;
  const int B = out_size / 16;
  const int* src = ei;
  const int* dst = ei + E;

  const int Np = (N + 3) & ~3;

  int* fill      = (int*)d_ws;                       // Np
  float* dinv    = (float*)(fill + Np);              // Np
  float* gatep   = dinv + Np;                        // Np
  int* gcount    = (int*)(gatep + Np);               // NBMAX
  float2* pstat  = (float2*)(gcount + NBMAX);        // B*POOL_S
  float* ppart   = (float*)(pstat + B * POOL_S);     // B*POOL_S*128
  int* srcs_pad  = (int*)(ppart + (size_t)B * POOL_S * 128);  // N*PAD_DEG
  ushort_t* Wt   = (ushort_t*)(srcs_pad + (size_t)N * PAD_DEG);  // 40960
  ushort_t* hs   = Wt + 40960;                       // (N+1)*128 bf16 (row N = zeros)
  ushort_t* h1   = hs + (size_t)128 * (N + 1);       // N*128 bf16 (h1, then h2)
  int* buckets   = (int*)h1;  // alias: NB*CAP*4 = 12.8MB < 25.6MB; dead by K3

  const int NB = (N + BUCKET_W - 1) >> BW_SH;   // 782
  const int nBin = (E + CHUNK - 1) / CHUNK;     // 196
  const int Gb64 = (N + 63) / 64;               // GEMM1 blocks
  const int Gg128 = (N + 127) / 128;            // GEMM2/gate blocks

  // K1: init (gcount=0, Wt prep, zero hs row N)
  int initIds = NBMAX + 40960 + 64;
  init_kernel<<<(initIds + 255) / 256, 256, 0, stream>>>(
      gcount, W1, W2, Wg1, Wt, (uint_t*)(hs + (size_t)128 * N));

  // K2: bin (pass A) || GEMM1, interleaved 1:1
  int nPairs = nBin > Gb64 ? nBin : Gb64;
  bin_gemm1_kernel<<<2 * nPairs, 256, 0, stream>>>(
      src, dst, gcount, buckets, E, x, Wt, hs, N, nBin, Gb64);

  // K2b: build (pass B): bucket lists -> fill + srcs_pad
  build_kernel<<<NB, 256, 0, stream>>>(gcount, buckets, fill, srcs_pad, N);

  // K3: aggregate1 (per-source dinv at gather time; writes dinv[])
  aggregate_ln_kernel<true><<<(N + 3) / 4, 256, 0, stream>>>(
      hs, fill, srcs_pad, dinv, b1, g1, be1, h1, N);
  // K4: GEMM2 (pre-scales output rows by dinv)
  gemm_mfma_kernel<128, true, false, false><<<Gg128, 256, 0, stream>>>(
      h1, Wt + 16384, nullptr, dinv, hs, N, nullptr, nullptr, nullptr);
  // K5: aggregate2 (rows pre-scaled; e = 1/0 only)
  aggregate_ln_kernel<false><<<(N + 3) / 4, 256, 0, stream>>>(
      hs, fill, srcs_pad, dinv, b2, g2, be2, h1, N);
  // K6: gate GEMM + fused dot
  gemm_mfma_kernel<64, false, true, true><<<Gg128, 256, 0, stream>>>(
      h1, Wt + 32768, bg1, nullptr, nullptr, N, Wg2, bg2, gatep);

  pool_partial_kernel<<<B * POOL_S, 256, 0, stream>>>(
      h1, gatep, bat, ppart, pstat, N);
  classify_kernel<<<B, 128, 0, stream>>>(ppart, pstat, Wc, bc, (float*)d_out);
}